// Round 1
// baseline (430.967 us; speedup 1.0000x reference)
//
#include <hip/hip_runtime.h>

// Problem constants (SymHQLinear): out = x[8192,4096] @ W^T, W[4096,4096]
// dequantized from codebook[4096,8] via indices + per-row scales + packed signs.
#define M_ 8192   // TOKENS
#define N_ 4096   // OUT
#define K_ 4096   // IN

typedef __bf16 bf16x8 __attribute__((ext_vector_type(8)));
typedef float  f32x4  __attribute__((ext_vector_type(4)));

__device__ __forceinline__ unsigned short f2bf(float f) {
  // round-to-nearest-even fp32 -> bf16
  unsigned u = __builtin_bit_cast(unsigned, f);
  unsigned r = 0x7fffu + ((u >> 16) & 1u);
  return (unsigned short)((u + r) >> 16);
}

// ---------------------------------------------------------------------------
// Kernel 1: dequantize W -> bf16 [N_][K_]  (one thread per 8-element group)
// w[8g+j] = codebook[idx[g]][j] * scales[row] * (bit(7-j) of signs[g] ? +1 : -1)
// ---------------------------------------------------------------------------
__global__ __launch_bounds__(256) void dequant_w_kernel(
    const float* __restrict__ cb, const float* __restrict__ scales,
    const int* __restrict__ idx, const int* __restrict__ signs,
    unsigned short* __restrict__ Wb)
{
  const int g   = blockIdx.x * 256 + threadIdx.x;   // group id (exact grid)
  const int row = g >> 9;                           // K_/8 = 512 groups per row
  const int code = idx[g];
  const int sb   = signs[g];
  const float s  = scales[row];
  const float* cv = cb + code * 8;

  unsigned short h[8];
#pragma unroll
  for (int j = 0; j < 8; ++j) {
    float v = cv[j] * s;
    if (!((sb >> (7 - j)) & 1)) v = -v;             // bit=1 -> +1, bit=0 -> -1
    h[j] = f2bf(v);
  }
  uint4 o;
  o.x = (unsigned)h[0] | ((unsigned)h[1] << 16);
  o.y = (unsigned)h[2] | ((unsigned)h[3] << 16);
  o.z = (unsigned)h[4] | ((unsigned)h[5] << 16);
  o.w = (unsigned)h[6] | ((unsigned)h[7] << 16);
  *(uint4*)(Wb + (size_t)g * 8) = o;
}

// ---------------------------------------------------------------------------
// Kernel 2: cast x fp32 -> bf16 (8 elements / thread, 32B in / 16B out)
// ---------------------------------------------------------------------------
__global__ __launch_bounds__(256) void cvt_x_kernel(
    const float* __restrict__ x, unsigned short* __restrict__ Xb)
{
  const size_t i = (size_t)blockIdx.x * 256 + threadIdx.x;  // exact grid
  const f32x4* px = (const f32x4*)(x + i * 8);
  f32x4 a = px[0], b = px[1];
  uint4 o;
  o.x = (unsigned)f2bf(a[0]) | ((unsigned)f2bf(a[1]) << 16);
  o.y = (unsigned)f2bf(a[2]) | ((unsigned)f2bf(a[3]) << 16);
  o.z = (unsigned)f2bf(b[0]) | ((unsigned)f2bf(b[1]) << 16);
  o.w = (unsigned)f2bf(b[2]) | ((unsigned)f2bf(b[3]) << 16);
  *(uint4*)(Xb + i * 8) = o;
}

// ---------------------------------------------------------------------------
// Kernel 3: C[M][N] = A[M][K] * B[N][K]^T, bf16 in / fp32 out.
// m97 structure: 128x128 tile, BK=32, 4 waves (2x2), global_load_lds width 16,
// 8 ds_read_b128 + 16 mfma_f32_16x16x32_bf16 per K-step, acc[4][4] per wave.
// ---------------------------------------------------------------------------
#define BM 128
#define BN 128
#define BK 32

__global__ __launch_bounds__(256) void gemm_bt_kernel(
    const unsigned short* __restrict__ A,   // [M_][K_] bf16 bits
    const unsigned short* __restrict__ B,   // [N_][K_] bf16 bits
    float* __restrict__ C)                  // [M_][N_]
{
  __shared__ unsigned short As[BM * BK];    // 8 KB
  __shared__ unsigned short Bs[BN * BK];    // 8 KB

  const int t    = threadIdx.x;
  const int lane = t & 63;
  const int wave = t >> 6;                  // 0..3
  const int wm   = wave >> 1;               // 0..1 (M half)
  const int wn   = wave & 1;                // 0..1 (N half)

  const int brow = blockIdx.y * BM;
  const int bcol = blockIdx.x * BN;

  // staging: vec8 index v in [0,512): row = v>>2, col8 = (v&3)*8.
  // LDS dest is linear (wave-uniform base + lane*16) as global_load_lds needs.
  const int v0 = t, v1 = t + 256;
  const int r0 = v0 >> 2, c0 = (v0 & 3) * 8;
  const int r1 = v1 >> 2, c1 = (v1 & 3) * 8;

  const unsigned short* gA0 = A + (size_t)(brow + r0) * K_ + c0;
  const unsigned short* gA1 = A + (size_t)(brow + r1) * K_ + c1;
  const unsigned short* gB0 = B + (size_t)(bcol + r0) * K_ + c0;
  const unsigned short* gB1 = B + (size_t)(bcol + r1) * K_ + c1;

  const int lrow = lane & 15;               // fragment row (A) / col (B)
  const int lk   = (lane >> 4) * 8;         // k offset within BK

  f32x4 acc[4][4];
#pragma unroll
  for (int i = 0; i < 4; ++i)
#pragma unroll
    for (int j = 0; j < 4; ++j)
      acc[i][j] = f32x4{0.f, 0.f, 0.f, 0.f};

  for (int k0 = 0; k0 < K_; k0 += BK) {
    __builtin_amdgcn_global_load_lds(
        (const __attribute__((address_space(1))) void*)(gA0 + k0),
        (__attribute__((address_space(3))) void*)(As + v0 * 8), 16, 0, 0);
    __builtin_amdgcn_global_load_lds(
        (const __attribute__((address_space(1))) void*)(gA1 + k0),
        (__attribute__((address_space(3))) void*)(As + v1 * 8), 16, 0, 0);
    __builtin_amdgcn_global_load_lds(
        (const __attribute__((address_space(1))) void*)(gB0 + k0),
        (__attribute__((address_space(3))) void*)(Bs + v0 * 8), 16, 0, 0);
    __builtin_amdgcn_global_load_lds(
        (const __attribute__((address_space(1))) void*)(gB1 + k0),
        (__attribute__((address_space(3))) void*)(Bs + v1 * 8), 16, 0, 0);
    asm volatile("s_waitcnt vmcnt(0)" ::: "memory");
    __syncthreads();

    bf16x8 af[4], bfr[4];
#pragma unroll
    for (int i = 0; i < 4; ++i) {
      af[i]  = *(const bf16x8*)(const void*)(As + (wm * 64 + i * 16 + lrow) * BK + lk);
      bfr[i] = *(const bf16x8*)(const void*)(Bs + (wn * 64 + i * 16 + lrow) * BK + lk);
    }
#pragma unroll
    for (int i = 0; i < 4; ++i)
#pragma unroll
      for (int j = 0; j < 4; ++j)
        acc[i][j] = __builtin_amdgcn_mfma_f32_16x16x32_bf16(af[i], bfr[j], acc[i][j], 0, 0, 0);

    __syncthreads();
  }

  // C/D layout (verified m89/m91): col = lane&15, row = (lane>>4)*4 + reg
  const int rbase = (lane >> 4) * 4;
#pragma unroll
  for (int i = 0; i < 4; ++i)
#pragma unroll
    for (int j = 0; j < 4; ++j)
#pragma unroll
      for (int r = 0; r < 4; ++r) {
        const int row = brow + wm * 64 + i * 16 + rbase + r;
        const int col = bcol + wn * 64 + j * 16 + lrow;
        C[(size_t)row * N_ + col] = acc[i][j][r];
      }
}

// ---------------------------------------------------------------------------
// Fallback (only if ws_size < 100.7 MB): fp32 tiled GEMM w/ on-the-fly dequant
// ---------------------------------------------------------------------------
__global__ __launch_bounds__(256) void fallback_kernel(
    const float* __restrict__ x, const float* __restrict__ cb,
    const float* __restrict__ scales, const int* __restrict__ idx,
    const int* __restrict__ signs, float* __restrict__ out)
{
  __shared__ float Xs[32][33];
  __shared__ float Ws[32][33];
  const int t = threadIdx.x;
  const int tx = t & 31, ty = t >> 5;       // ty 0..7
  const int brow = blockIdx.y * 32, bcol = blockIdx.x * 32;
  float acc[4] = {0.f, 0.f, 0.f, 0.f};

  for (int k0 = 0; k0 < K_; k0 += 32) {
    for (int l = t; l < 1024; l += 256) {
      const int r = l >> 5, c = l & 31;
      Xs[r][c] = x[(size_t)(brow + r) * K_ + k0 + c];
      const int n = bcol + r;
      const size_t flat = (size_t)n * K_ + (k0 + c);
      const int g = (int)(flat >> 3), j = (int)(flat & 7);
      float wv = cb[idx[g] * 8 + j] * scales[n];
      if (!((signs[g] >> (7 - j)) & 1)) wv = -wv;
      Ws[r][c] = wv;
    }
    __syncthreads();
#pragma unroll
    for (int kk = 0; kk < 32; ++kk) {
      const float wv = Ws[tx][kk];
      acc[0] += Xs[ty][kk] * wv;
      acc[1] += Xs[ty + 8][kk] * wv;
      acc[2] += Xs[ty + 16][kk] * wv;
      acc[3] += Xs[ty + 24][kk] * wv;
    }
    __syncthreads();
  }
#pragma unroll
  for (int q = 0; q < 4; ++q)
    out[(size_t)(brow + ty + 8 * q) * N_ + bcol + tx] = acc[q];
}

// ---------------------------------------------------------------------------
extern "C" void kernel_launch(void* const* d_in, const int* in_sizes, int n_in,
                              void* d_out, int out_size, void* d_ws, size_t ws_size,
                              hipStream_t stream)
{
  const float* x      = (const float*)d_in[0];
  const float* cb     = (const float*)d_in[1];
  const float* scales = (const float*)d_in[2];
  const int*   idx    = (const int*)d_in[3];
  const int*   signs  = (const int*)d_in[4];
  float* out = (float*)d_out;

  const size_t wbytes = (size_t)N_ * K_ * 2;   // 33.55 MB bf16 W
  const size_t xbytes = (size_t)M_ * K_ * 2;   // 67.11 MB bf16 X

  if (ws_size >= wbytes + xbytes) {
    unsigned short* Wb = (unsigned short*)d_ws;
    unsigned short* Xb = (unsigned short*)((char*)d_ws + wbytes);
    dequant_w_kernel<<<(N_ * K_ / 8) / 256, 256, 0, stream>>>(cb, scales, idx, signs, Wb);
    cvt_x_kernel<<<(M_ * K_ / 8) / 256, 256, 0, stream>>>(x, Xb);
    gemm_bt_kernel<<<dim3(N_ / BN, M_ / BM), 256, 0, stream>>>(Xb, Wb, out);
  } else {
    fallback_kernel<<<dim3(N_ / 32, M_ / 32), 256, 0, stream>>>(x, cb, scales, idx, signs, out);
  }
}

// Round 2
// 287.200 us; speedup vs baseline: 1.5006x; 1.5006x over previous
//
#include <hip/hip_runtime.h>

// SymHQLinear: out[8192,4096] = x @ W^T; W[4096,4096] dequantized from
// codebook[4096,8] + per-row scales + packed sign bits.
#define M_ 8192   // TOKENS
#define N_ 4096   // OUT
#define K_ 4096   // IN

typedef __bf16 bf16x8 __attribute__((ext_vector_type(8)));
typedef float  f32x4  __attribute__((ext_vector_type(4)));

__device__ __forceinline__ unsigned short f2bf(float f) {
  unsigned u = __builtin_bit_cast(unsigned, f);
  unsigned r = 0x7fffu + ((u >> 16) & 1u);
  return (unsigned short)((u + r) >> 16);
}

// ---------------------------------------------------------------------------
// Kernel 1: dequantize W -> bf16 [N_][K_]
// ---------------------------------------------------------------------------
__global__ __launch_bounds__(256) void dequant_w_kernel(
    const float* __restrict__ cb, const float* __restrict__ scales,
    const int* __restrict__ idx, const int* __restrict__ signs,
    unsigned short* __restrict__ Wb)
{
  const int g   = blockIdx.x * 256 + threadIdx.x;
  const int row = g >> 9;                           // 512 groups per row
  const int code = idx[g];
  const int sb   = signs[g];
  const float s  = scales[row];
  const float* cv = cb + code * 8;

  unsigned short h[8];
#pragma unroll
  for (int j = 0; j < 8; ++j) {
    float v = cv[j] * s;
    if (!((sb >> (7 - j)) & 1)) v = -v;
    h[j] = f2bf(v);
  }
  uint4 o;
  o.x = (unsigned)h[0] | ((unsigned)h[1] << 16);
  o.y = (unsigned)h[2] | ((unsigned)h[3] << 16);
  o.z = (unsigned)h[4] | ((unsigned)h[5] << 16);
  o.w = (unsigned)h[6] | ((unsigned)h[7] << 16);
  *(uint4*)(Wb + (size_t)g * 8) = o;
}

// ---------------------------------------------------------------------------
// Kernel 2: cast x fp32 -> bf16
// ---------------------------------------------------------------------------
__global__ __launch_bounds__(256) void cvt_x_kernel(
    const float* __restrict__ x, unsigned short* __restrict__ Xb)
{
  const size_t i = (size_t)blockIdx.x * 256 + threadIdx.x;
  const f32x4* px = (const f32x4*)(x + i * 8);
  f32x4 a = px[0], b = px[1];
  uint4 o;
  o.x = (unsigned)f2bf(a[0]) | ((unsigned)f2bf(a[1]) << 16);
  o.y = (unsigned)f2bf(a[2]) | ((unsigned)f2bf(a[3]) << 16);
  o.z = (unsigned)f2bf(b[0]) | ((unsigned)f2bf(b[1]) << 16);
  o.w = (unsigned)f2bf(b[2]) | ((unsigned)f2bf(b[3]) << 16);
  *(uint4*)(Xb + i * 8) = o;
}

// ---------------------------------------------------------------------------
// Kernel 3: 256x256x64 8-phase GEMM, C = A[M][K] * B[N][K]^T, bf16->fp32.
// 8 waves (2M x 4N), 128 KiB LDS = 2 bufs x 4 half-tiles (128x64 bf16).
// Swizzle: 16B-chunk index ^= (row&7)  (involution; linear global_load_lds
// dest + inverse-swizzled global SOURCE + swizzled ds_read addr).
// Counted vmcnt(8) once per tile; drains only for the last 2 tiles.
// ---------------------------------------------------------------------------
#define BM 256
#define BN 256
#define BK 64
#define NT (K_ / BK)          // 64 K-tiles
#define HTE 8192              // bf16 elems per half-tile (128 x 64)

#define GLDS(g, l) __builtin_amdgcn_global_load_lds( \
    (const __attribute__((address_space(1))) void*)(g), \
    (__attribute__((address_space(3))) void*)(l), 16, 0, 0)

template<int VM, bool STAGE>
__device__ __forceinline__ void tile_step(
    int t,
    unsigned short (*lds)[HTE],            // [8][HTE]: buf*4 + region
    f32x4 (&acc)[8][4],
    const unsigned short* __restrict__ Ag, // Xb + brow*K_
    const unsigned short* __restrict__ Bg, // Wb + bcol*K_
    int wm, int wnl, int bsel,
    int lrow, int hi2, int sw,
    int w, int lane, int srow, int scw8)
{
  unsigned short* Lb = lds[(t & 1) * 4];
  const unsigned short* Ab = Lb + wm * HTE;          // this wave's A half-tile
  const unsigned short* Bb = Lb + (2 + bsel) * HTE;  // this wave's B half-tile

  bf16x8 af[4][2], blo[2][2], bhi[2][2];

  // ---- P0: ds-read A quad0 (8) + B lo (4); MFMA (m0-3 x n0-1) ----
#pragma unroll
  for (int m = 0; m < 4; ++m)
#pragma unroll
    for (int ks = 0; ks < 2; ++ks)
      af[m][ks] = *(const bf16x8*)(const void*)(
          Ab + (m * 16 + lrow) * 64 + (((ks * 4 + hi2) ^ sw) * 8));
#pragma unroll
  for (int n = 0; n < 2; ++n)
#pragma unroll
    for (int ks = 0; ks < 2; ++ks)
      blo[n][ks] = *(const bf16x8*)(const void*)(
          Bb + (wnl * 64 + n * 16 + lrow) * 64 + (((ks * 4 + hi2) ^ sw) * 8));
  __builtin_amdgcn_s_barrier();
  asm volatile("s_waitcnt lgkmcnt(0)" ::: "memory");
  __builtin_amdgcn_s_setprio(1);
#pragma unroll
  for (int m = 0; m < 4; ++m)
#pragma unroll
    for (int n = 0; n < 2; ++n)
#pragma unroll
      for (int ks = 0; ks < 2; ++ks)
        acc[m][n] = __builtin_amdgcn_mfma_f32_16x16x32_bf16(af[m][ks], blo[n][ks], acc[m][n], 0, 0, 0);
  __builtin_amdgcn_s_setprio(0);
  __builtin_amdgcn_s_barrier();

  // ---- P1: ds-read B hi (4); MFMA (m0-3 x n2-3) ----
#pragma unroll
  for (int n = 0; n < 2; ++n)
#pragma unroll
    for (int ks = 0; ks < 2; ++ks)
      bhi[n][ks] = *(const bf16x8*)(const void*)(
          Bb + (wnl * 64 + (2 + n) * 16 + lrow) * 64 + (((ks * 4 + hi2) ^ sw) * 8));
  __builtin_amdgcn_s_barrier();
  asm volatile("s_waitcnt lgkmcnt(0)" ::: "memory");
  __builtin_amdgcn_s_setprio(1);
#pragma unroll
  for (int m = 0; m < 4; ++m)
#pragma unroll
    for (int n = 0; n < 2; ++n)
#pragma unroll
      for (int ks = 0; ks < 2; ++ks)
        acc[m][2 + n] = __builtin_amdgcn_mfma_f32_16x16x32_bf16(af[m][ks], bhi[n][ks], acc[m][2 + n], 0, 0, 0);
  __builtin_amdgcn_s_setprio(0);
  __builtin_amdgcn_s_barrier();

  // ---- P2: ds-read A quad1 (8); stage B-lo(t+2); MFMA (m4-7 x n0-1) ----
#pragma unroll
  for (int m = 0; m < 4; ++m)
#pragma unroll
    for (int ks = 0; ks < 2; ++ks)
      af[m][ks] = *(const bf16x8*)(const void*)(
          Ab + ((4 + m) * 16 + lrow) * 64 + (((ks * 4 + hi2) ^ sw) * 8));
  if (STAGE) {
#pragma unroll
    for (int i = 0; i < 2; ++i)
      GLDS(Bg + (size_t)(srow + i * 8) * K_ + (t + 2) * BK + scw8,
           Lb + 2 * HTE + (w * 128 + i * 64 + lane) * 8);
  }
  __builtin_amdgcn_s_barrier();
  asm volatile("s_waitcnt lgkmcnt(0)" ::: "memory");
  __builtin_amdgcn_s_setprio(1);
#pragma unroll
  for (int m = 0; m < 4; ++m)
#pragma unroll
    for (int n = 0; n < 2; ++n)
#pragma unroll
      for (int ks = 0; ks < 2; ++ks)
        acc[4 + m][n] = __builtin_amdgcn_mfma_f32_16x16x32_bf16(af[m][ks], blo[n][ks], acc[4 + m][n], 0, 0, 0);
  __builtin_amdgcn_s_setprio(0);
  __builtin_amdgcn_s_barrier();

  // ---- P3: stage B-hi, A-lo, A-hi (t+2); MFMA (m4-7 x n2-3); vmcnt ----
  if (STAGE) {
#pragma unroll
    for (int i = 0; i < 2; ++i)
      GLDS(Bg + (size_t)(128 + srow + i * 8) * K_ + (t + 2) * BK + scw8,
           Lb + 3 * HTE + (w * 128 + i * 64 + lane) * 8);
#pragma unroll
    for (int i = 0; i < 2; ++i)
      GLDS(Ag + (size_t)(srow + i * 8) * K_ + (t + 2) * BK + scw8,
           Lb + 0 * HTE + (w * 128 + i * 64 + lane) * 8);
#pragma unroll
    for (int i = 0; i < 2; ++i)
      GLDS(Ag + (size_t)(128 + srow + i * 8) * K_ + (t + 2) * BK + scw8,
           Lb + 1 * HTE + (w * 128 + i * 64 + lane) * 8);
  }
  __builtin_amdgcn_s_barrier();
  __builtin_amdgcn_s_setprio(1);
#pragma unroll
  for (int m = 0; m < 4; ++m)
#pragma unroll
    for (int n = 0; n < 2; ++n)
#pragma unroll
      for (int ks = 0; ks < 2; ++ks)
        acc[4 + m][2 + n] = __builtin_amdgcn_mfma_f32_16x16x32_bf16(af[m][ks], bhi[n][ks], acc[4 + m][2 + n], 0, 0, 0);
  __builtin_amdgcn_s_setprio(0);
  if constexpr (VM == 8)
    asm volatile("s_waitcnt vmcnt(8)" ::: "memory");
  else
    asm volatile("s_waitcnt vmcnt(0)" ::: "memory");
  __builtin_amdgcn_s_barrier();
}

__global__ __launch_bounds__(512, 2) void gemm256_kernel(
    const unsigned short* __restrict__ A,   // Xb [M_][K_]
    const unsigned short* __restrict__ B,   // Wb [N_][K_]
    float* __restrict__ C)
{
  __shared__ unsigned short lds[8][HTE];    // 128 KiB

  // XCD-aware bijective swizzle (nwg = 512, 512 % 8 == 0)
  const int nwg = (M_ / BM) * (N_ / BN);
  const int bid = blockIdx.x;
  const int wg  = (bid % 8) * (nwg / 8) + bid / 8;
  const int tn  = wg % (N_ / BN);
  const int tm  = wg / (N_ / BN);
  const int brow = tm * BM, bcol = tn * BN;

  const int tid  = threadIdx.x;
  const int lane = tid & 63, w = tid >> 6;
  const int wm   = w >> 2, wn = w & 3;      // 2 (M) x 4 (N)
  const int wnl  = wn & 1, bsel = wn >> 1;
  const int lrow = lane & 15, hi2 = lane >> 4, sw = lrow & 7;
  // staging: thread owns chunks p = w*128 + i*64 + lane (i=0,1)
  const int srow = w * 16 + (lane >> 3);
  const int scw8 = ((lane & 7) ^ (lane >> 3)) * 8;   // inverse-swizzled col

  const unsigned short* Ag = A + (size_t)brow * K_;
  const unsigned short* Bg = B + (size_t)bcol * K_;

  f32x4 acc[8][4];
#pragma unroll
  for (int m = 0; m < 8; ++m)
#pragma unroll
    for (int n = 0; n < 4; ++n)
      acc[m][n] = f32x4{0.f, 0.f, 0.f, 0.f};

  // prologue: stage tile 0 (buf0) then tile 1 (buf1); wait tile0, barrier.
#pragma unroll
  for (int tt = 0; tt < 2; ++tt) {
    unsigned short* Lb = lds[tt * 4];
#pragma unroll
    for (int i = 0; i < 2; ++i) {
      const int r = srow + i * 8;
      const int dst = (w * 128 + i * 64 + lane) * 8;
      GLDS(Ag + (size_t)r * K_ + tt * BK + scw8,         Lb + 0 * HTE + dst);
      GLDS(Ag + (size_t)(128 + r) * K_ + tt * BK + scw8, Lb + 1 * HTE + dst);
      GLDS(Bg + (size_t)r * K_ + tt * BK + scw8,         Lb + 2 * HTE + dst);
      GLDS(Bg + (size_t)(128 + r) * K_ + tt * BK + scw8, Lb + 3 * HTE + dst);
    }
  }
  asm volatile("s_waitcnt vmcnt(8)" ::: "memory");
  __builtin_amdgcn_s_barrier();

  for (int t = 0; t < NT - 2; ++t)
    tile_step<8, true>(t, lds, acc, Ag, Bg, wm, wnl, bsel, lrow, hi2, sw, w, lane, srow, scw8);
  tile_step<0, false>(NT - 2, lds, acc, Ag, Bg, wm, wnl, bsel, lrow, hi2, sw, w, lane, srow, scw8);
  tile_step<0, false>(NT - 1, lds, acc, Ag, Bg, wm, wnl, bsel, lrow, hi2, sw, w, lane, srow, scw8);

  // epilogue: C/D layout col = lane&15, row = (lane>>4)*4 + reg
  const int crow = brow + wm * 128 + hi2 * 4;
  const int ccol = bcol + wn * 64 + lrow;
#pragma unroll
  for (int m = 0; m < 8; ++m)
#pragma unroll
    for (int n = 0; n < 4; ++n)
#pragma unroll
      for (int r = 0; r < 4; ++r)
        C[(size_t)(crow + m * 16 + r) * N_ + ccol + n * 16] = acc[m][n][r];
}

// ---------------------------------------------------------------------------
// Fallback (ws too small): fp32 tiled GEMM with on-the-fly dequant
// ---------------------------------------------------------------------------
__global__ __launch_bounds__(256) void fallback_kernel(
    const float* __restrict__ x, const float* __restrict__ cb,
    const float* __restrict__ scales, const int* __restrict__ idx,
    const int* __restrict__ signs, float* __restrict__ out)
{
  __shared__ float Xs[32][33];
  __shared__ float Ws[32][33];
  const int t = threadIdx.x;
  const int tx = t & 31, ty = t >> 5;
  const int brow = blockIdx.y * 32, bcol = blockIdx.x * 32;
  float acc[4] = {0.f, 0.f, 0.f, 0.f};

  for (int k0 = 0; k0 < K_; k0 += 32) {
    for (int l = t; l < 1024; l += 256) {
      const int r = l >> 5, c = l & 31;
      Xs[r][c] = x[(size_t)(brow + r) * K_ + k0 + c];
      const int n = bcol + r;
      const size_t flat = (size_t)n * K_ + (k0 + c);
      const int g = (int)(flat >> 3), j = (int)(flat & 7);
      float wv = cb[idx[g] * 8 + j] * scales[n];
      if (!((signs[g] >> (7 - j)) & 1)) wv = -wv;
      Ws[r][c] = wv;
    }
    __syncthreads();
#pragma unroll
    for (int kk = 0; kk < 32; ++kk) {
      const float wv = Ws[tx][kk];
      acc[0] += Xs[ty][kk] * wv;
      acc[1] += Xs[ty + 8][kk] * wv;
      acc[2] += Xs[ty + 16][kk] * wv;
      acc[3] += Xs[ty + 24][kk] * wv;
    }
    __syncthreads();
  }
#pragma unroll
  for (int q = 0; q < 4; ++q)
    out[(size_t)(brow + ty + 8 * q) * N_ + bcol + tx] = acc[q];
}

// ---------------------------------------------------------------------------
extern "C" void kernel_launch(void* const* d_in, const int* in_sizes, int n_in,
                              void* d_out, int out_size, void* d_ws, size_t ws_size,
                              hipStream_t stream)
{
  const float* x      = (const float*)d_in[0];
  const float* cb     = (const float*)d_in[1];
  const float* scales = (const float*)d_in[2];
  const int*   idx    = (const int*)d_in[3];
  const int*   signs  = (const int*)d_in[4];
  float* out = (float*)d_out;

  const size_t wbytes = (size_t)N_ * K_ * 2;
  const size_t xbytes = (size_t)M_ * K_ * 2;

  if (ws_size >= wbytes + xbytes) {
    unsigned short* Wb = (unsigned short*)d_ws;
    unsigned short* Xb = (unsigned short*)((char*)d_ws + wbytes);
    dequant_w_kernel<<<(N_ * K_ / 8) / 256, 256, 0, stream>>>(cb, scales, idx, signs, Wb);
    cvt_x_kernel<<<(M_ * K_ / 8) / 256, 256, 0, stream>>>(x, Xb);
    gemm256_kernel<<<(M_ / BM) * (N_ / BN), 512, 0, stream>>>(Xb, Wb, out);
  } else {
    fallback_kernel<<<dim3(N_ / 32, M_ / 32), 256, 0, stream>>>(x, cb, scales, idx, signs, out);
  }
}

// Round 3
// 281.402 us; speedup vs baseline: 1.5315x; 1.0206x over previous
//
#include <hip/hip_runtime.h>

// SymHQLinear: out[8192,4096] = x @ W^T; W[4096,4096] dequantized from
// codebook[4096,8] + per-row scales + packed sign bits.
#define M_ 8192   // TOKENS
#define N_ 4096   // OUT
#define K_ 4096   // IN

typedef __bf16 bf16x8 __attribute__((ext_vector_type(8)));
typedef float  f32x4  __attribute__((ext_vector_type(4)));

__device__ __forceinline__ unsigned short f2bf(float f) {
  unsigned u = __builtin_bit_cast(unsigned, f);
  unsigned r = 0x7fffu + ((u >> 16) & 1u);
  return (unsigned short)((u + r) >> 16);
}

// ---------------------------------------------------------------------------
// Kernel 1: dequantize W -> bf16 [N_][K_]
// ---------------------------------------------------------------------------
__global__ __launch_bounds__(256) void dequant_w_kernel(
    const float* __restrict__ cb, const float* __restrict__ scales,
    const int* __restrict__ idx, const int* __restrict__ signs,
    unsigned short* __restrict__ Wb)
{
  const int g   = blockIdx.x * 256 + threadIdx.x;
  const int row = g >> 9;                           // 512 groups per row
  const int code = idx[g];
  const int sb   = signs[g];
  const float s  = scales[row];
  const float* cv = cb + code * 8;

  unsigned short h[8];
#pragma unroll
  for (int j = 0; j < 8; ++j) {
    float v = cv[j] * s;
    if (!((sb >> (7 - j)) & 1)) v = -v;
    h[j] = f2bf(v);
  }
  uint4 o;
  o.x = (unsigned)h[0] | ((unsigned)h[1] << 16);
  o.y = (unsigned)h[2] | ((unsigned)h[3] << 16);
  o.z = (unsigned)h[4] | ((unsigned)h[5] << 16);
  o.w = (unsigned)h[6] | ((unsigned)h[7] << 16);
  *(uint4*)(Wb + (size_t)g * 8) = o;
}

// ---------------------------------------------------------------------------
// Kernel 2: cast x fp32 -> bf16
// ---------------------------------------------------------------------------
__global__ __launch_bounds__(256) void cvt_x_kernel(
    const float* __restrict__ x, unsigned short* __restrict__ Xb)
{
  const size_t i = (size_t)blockIdx.x * 256 + threadIdx.x;
  const f32x4* px = (const f32x4*)(x + i * 8);
  f32x4 a = px[0], b = px[1];
  uint4 o;
  o.x = (unsigned)f2bf(a[0]) | ((unsigned)f2bf(a[1]) << 16);
  o.y = (unsigned)f2bf(a[2]) | ((unsigned)f2bf(a[3]) << 16);
  o.z = (unsigned)f2bf(b[0]) | ((unsigned)f2bf(b[1]) << 16);
  o.w = (unsigned)f2bf(b[2]) | ((unsigned)f2bf(b[3]) << 16);
  *(uint4*)(Xb + i * 8) = o;
}

// ---------------------------------------------------------------------------
// Kernel 3: 256x256x64 GEMM, pipelined 4-phase schedule.
// Phase p issues ds_reads for phase p+1; counted lgkmcnt before MFMA so the
// LDS unit serves reads DURING the MFMA region (overlap, not sum).
// Phases: P0 q0xblo, P1 q0xbhi, P2 q1xblo, P3 q1xbhi.
// Reads:  P0 bhi(4), P1 aq1(8), P2 next aq0'(8), P3 next blo'(4).
// Stages: P1 r2(B-lo), P2 r3(B-hi), P3 r0+r1(A)  -- each after its region's
// last read was confirmed drained by a prior counted lgkmcnt (DS in-order).
// vmcnt(2) at end of P1 drains next-tile's 8 loads before cross-buffer reads.
// ---------------------------------------------------------------------------
#define BM 256
#define BN 256
#define BK 64
#define NT (K_ / BK)          // 64 K-tiles
#define HTE 8192              // bf16 elems per half-tile (128 x 64)

#define GLDS(g, l) __builtin_amdgcn_global_load_lds( \
    (const __attribute__((address_space(1))) void*)(g), \
    (__attribute__((address_space(3))) void*)(l), 16, 0, 0)

#define LGKM_WAIT(n) do { \
    asm volatile("s_waitcnt lgkmcnt(" #n ")" ::: "memory"); \
    __builtin_amdgcn_sched_barrier(0); \
  } while (0)

// MODE: 0 = steady, 1 = t==NT-2 (no stage, vmcnt(0)), 2 = t==NT-1 (tail)
template<int MODE>
__device__ __forceinline__ void tile_step(
    int t, unsigned short (*lds)[HTE], f32x4 (&acc)[8][4],
    bf16x8 (&aq0)[4][2], bf16x8 (&aq1)[4][2],
    bf16x8 (&bl)[2][2], bf16x8 (&bh)[2][2],
    const unsigned short* __restrict__ Ag,
    const unsigned short* __restrict__ Bg,
    int wm, int wnl, int bsel, int lrow, int hi2, int sw,
    int w, int lane, int srow, int scw8)
{
  unsigned short* Lb = lds[(t & 1) * 4];
  unsigned short* Ln = lds[((t + 1) & 1) * 4];
  const unsigned short* Ab = Lb + wm * HTE;
  const unsigned short* Bb = Lb + (2 + bsel) * HTE;
  const unsigned short* An = Ln + wm * HTE;
  const unsigned short* Bn = Ln + (2 + bsel) * HTE;
  const int dst = (w * 128 + lane) * 8;             // staging chunk i=0
  const int dst1 = (w * 128 + 64 + lane) * 8;       // staging chunk i=1

  // ================= P0: read bhi (for P1); MFMA q0 x blo =================
#pragma unroll
  for (int n = 0; n < 2; ++n)
#pragma unroll
    for (int ks = 0; ks < 2; ++ks)
      bh[n][ks] = *(const bf16x8*)(const void*)(
          Bb + (wnl * 64 + (2 + n) * 16 + lrow) * 64 + (((ks * 4 + hi2) ^ sw) * 8));
  __builtin_amdgcn_s_barrier();
  LGKM_WAIT(4);                       // aq0 + bl (issued prev P2/P3) ready
  __builtin_amdgcn_s_setprio(1);
#pragma unroll
  for (int m = 0; m < 4; ++m)
#pragma unroll
    for (int n = 0; n < 2; ++n)
#pragma unroll
      for (int ks = 0; ks < 2; ++ks)
        acc[m][n] = __builtin_amdgcn_mfma_f32_16x16x32_bf16(aq0[m][ks], bl[n][ks], acc[m][n], 0, 0, 0);
  __builtin_amdgcn_s_setprio(0);
  __builtin_amdgcn_s_barrier();

  // ========== P1: read aq1 (for P2); stage r2; MFMA q0 x bhi; vmcnt =======
#pragma unroll
  for (int m = 0; m < 4; ++m)
#pragma unroll
    for (int ks = 0; ks < 2; ++ks)
      aq1[m][ks] = *(const bf16x8*)(const void*)(
          Ab + ((4 + m) * 16 + lrow) * 64 + (((ks * 4 + hi2) ^ sw) * 8));
  if (MODE == 0) {
    GLDS(Bg + (size_t)(srow) * K_ + (t + 2) * BK + scw8,     Lb + 2 * HTE + dst);
    GLDS(Bg + (size_t)(srow + 8) * K_ + (t + 2) * BK + scw8, Lb + 2 * HTE + dst1);
  }
  __builtin_amdgcn_s_barrier();
  LGKM_WAIT(8);                       // bh (issued P0) ready
  __builtin_amdgcn_s_setprio(1);
#pragma unroll
  for (int m = 0; m < 4; ++m)
#pragma unroll
    for (int n = 0; n < 2; ++n)
#pragma unroll
      for (int ks = 0; ks < 2; ++ks)
        acc[m][2 + n] = __builtin_amdgcn_mfma_f32_16x16x32_bf16(aq0[m][ks], bh[n][ks], acc[m][2 + n], 0, 0, 0);
  __builtin_amdgcn_s_setprio(0);
  if (MODE == 0)
    asm volatile("s_waitcnt vmcnt(2)" ::: "memory");   // next-tile buffer landed
  else if (MODE == 1)
    asm volatile("s_waitcnt vmcnt(0)" ::: "memory");   // final tile's loads
  __builtin_amdgcn_s_barrier();

  // ===== P2: read next aq0' (for t+1 P0); stage r3; MFMA q1 x blo ========
  if (MODE < 2) {
#pragma unroll
    for (int m = 0; m < 4; ++m)
#pragma unroll
      for (int ks = 0; ks < 2; ++ks)
        aq0[m][ks] = *(const bf16x8*)(const void*)(
            An + (m * 16 + lrow) * 64 + (((ks * 4 + hi2) ^ sw) * 8));
  }
  if (MODE == 0) {
    GLDS(Bg + (size_t)(128 + srow) * K_ + (t + 2) * BK + scw8,     Lb + 3 * HTE + dst);
    GLDS(Bg + (size_t)(128 + srow + 8) * K_ + (t + 2) * BK + scw8, Lb + 3 * HTE + dst1);
  }
  __builtin_amdgcn_s_barrier();
  if (MODE < 2) { LGKM_WAIT(8); } else { LGKM_WAIT(0); }   // aq1 ready
  __builtin_amdgcn_s_setprio(1);
#pragma unroll
  for (int m = 0; m < 4; ++m)
#pragma unroll
    for (int n = 0; n < 2; ++n)
#pragma unroll
      for (int ks = 0; ks < 2; ++ks)
        acc[4 + m][n] = __builtin_amdgcn_mfma_f32_16x16x32_bf16(aq1[m][ks], bl[n][ks], acc[4 + m][n], 0, 0, 0);
  __builtin_amdgcn_s_setprio(0);
  __builtin_amdgcn_s_barrier();

  // ===== P3: read next blo' (for t+1 P0); stage r0+r1; MFMA q1 x bhi =====
  if (MODE < 2) {
#pragma unroll
    for (int n = 0; n < 2; ++n)
#pragma unroll
      for (int ks = 0; ks < 2; ++ks)
        bl[n][ks] = *(const bf16x8*)(const void*)(
            Bn + (wnl * 64 + n * 16 + lrow) * 64 + (((ks * 4 + hi2) ^ sw) * 8));
  }
  if (MODE == 0) {
    GLDS(Ag + (size_t)(srow) * K_ + (t + 2) * BK + scw8,           Lb + 0 * HTE + dst);
    GLDS(Ag + (size_t)(srow + 8) * K_ + (t + 2) * BK + scw8,       Lb + 0 * HTE + dst1);
    GLDS(Ag + (size_t)(128 + srow) * K_ + (t + 2) * BK + scw8,     Lb + 1 * HTE + dst);
    GLDS(Ag + (size_t)(128 + srow + 8) * K_ + (t + 2) * BK + scw8, Lb + 1 * HTE + dst1);
  }
  __builtin_amdgcn_s_barrier();
  // no lgkm wait: aq1 confirmed at P2's wait, bh at P1's wait
  __builtin_amdgcn_s_setprio(1);
#pragma unroll
  for (int m = 0; m < 4; ++m)
#pragma unroll
    for (int n = 0; n < 2; ++n)
#pragma unroll
      for (int ks = 0; ks < 2; ++ks)
        acc[4 + m][2 + n] = __builtin_amdgcn_mfma_f32_16x16x32_bf16(aq1[m][ks], bh[n][ks], acc[4 + m][2 + n], 0, 0, 0);
  __builtin_amdgcn_s_setprio(0);
  __builtin_amdgcn_s_barrier();
}

__global__ __launch_bounds__(512, 2) void gemm256_kernel(
    const unsigned short* __restrict__ A,   // Xb [M_][K_]
    const unsigned short* __restrict__ B,   // Wb [N_][K_]
    float* __restrict__ C)
{
  __shared__ unsigned short lds[8][HTE];    // 128 KiB

  // XCD-aware bijective swizzle (nwg = 512, 512 % 8 == 0)
  const int nwg = (M_ / BM) * (N_ / BN);
  const int bid = blockIdx.x;
  const int wg  = (bid % 8) * (nwg / 8) + bid / 8;
  const int tn  = wg % (N_ / BN);
  const int tm  = wg / (N_ / BN);
  const int brow = tm * BM, bcol = tn * BN;

  const int tid  = threadIdx.x;
  const int lane = tid & 63, w = tid >> 6;
  const int wm   = w >> 2, wn = w & 3;      // 2 (M) x 4 (N)
  const int wnl  = wn & 1, bsel = wn >> 1;
  const int lrow = lane & 15, hi2 = lane >> 4, sw = lrow & 7;
  const int srow = w * 16 + (lane >> 3);
  const int scw8 = ((lane & 7) ^ (lane >> 3)) * 8;   // inverse-swizzled col

  const unsigned short* Ag = A + (size_t)brow * K_;
  const unsigned short* Bg = B + (size_t)bcol * K_;

  f32x4 acc[8][4];
#pragma unroll
  for (int m = 0; m < 8; ++m)
#pragma unroll
    for (int n = 0; n < 4; ++n)
      acc[m][n] = f32x4{0.f, 0.f, 0.f, 0.f};

  // prologue: stage tile 0 -> buf0 (first!), tile 1 -> buf1
#pragma unroll
  for (int tt = 0; tt < 2; ++tt) {
    unsigned short* Lb = lds[tt * 4];
#pragma unroll
    for (int i = 0; i < 2; ++i) {
      const int r = srow + i * 8;
      const int d = (w * 128 + i * 64 + lane) * 8;
      GLDS(Ag + (size_t)r * K_ + tt * BK + scw8,         Lb + 0 * HTE + d);
      GLDS(Ag + (size_t)(128 + r) * K_ + tt * BK + scw8, Lb + 1 * HTE + d);
      GLDS(Bg + (size_t)r * K_ + tt * BK + scw8,         Lb + 2 * HTE + d);
      GLDS(Bg + (size_t)(128 + r) * K_ + tt * BK + scw8, Lb + 3 * HTE + d);
    }
  }
  asm volatile("s_waitcnt vmcnt(8)" ::: "memory");     // tile 0 landed
  __builtin_amdgcn_s_barrier();

  // pre-read tile0 P0 operands (aq0 quad0 + blo), buf0
  bf16x8 aq0[4][2], aq1[4][2], bl[2][2], bh[2][2];
  {
    const unsigned short* Ab = lds[0] + wm * HTE;
    const unsigned short* Bb = lds[0] + (2 + bsel) * HTE;
#pragma unroll
    for (int m = 0; m < 4; ++m)
#pragma unroll
      for (int ks = 0; ks < 2; ++ks)
        aq0[m][ks] = *(const bf16x8*)(const void*)(
            Ab + (m * 16 + lrow) * 64 + (((ks * 4 + hi2) ^ sw) * 8));
#pragma unroll
    for (int n = 0; n < 2; ++n)
#pragma unroll
      for (int ks = 0; ks < 2; ++ks)
        bl[n][ks] = *(const bf16x8*)(const void*)(
            Bb + (wnl * 64 + n * 16 + lrow) * 64 + (((ks * 4 + hi2) ^ sw) * 8));
  }

  for (int t = 0; t < NT - 2; ++t)
    tile_step<0>(t, lds, acc, aq0, aq1, bl, bh, Ag, Bg,
                 wm, wnl, bsel, lrow, hi2, sw, w, lane, srow, scw8);
  tile_step<1>(NT - 2, lds, acc, aq0, aq1, bl, bh, Ag, Bg,
               wm, wnl, bsel, lrow, hi2, sw, w, lane, srow, scw8);
  tile_step<2>(NT - 1, lds, acc, aq0, aq1, bl, bh, Ag, Bg,
               wm, wnl, bsel, lrow, hi2, sw, w, lane, srow, scw8);

  // epilogue: C/D layout col = lane&15, row = (lane>>4)*4 + reg
  const int crow = brow + wm * 128 + hi2 * 4;
  const int ccol = bcol + wn * 64 + lrow;
#pragma unroll
  for (int m = 0; m < 8; ++m)
#pragma unroll
    for (int n = 0; n < 4; ++n)
#pragma unroll
      for (int r = 0; r < 4; ++r)
        C[(size_t)(crow + m * 16 + r) * N_ + ccol + n * 16] = acc[m][n][r];
}

// ---------------------------------------------------------------------------
// Fallback (ws too small): fp32 tiled GEMM with on-the-fly dequant
// ---------------------------------------------------------------------------
__global__ __launch_bounds__(256) void fallback_kernel(
    const float* __restrict__ x, const float* __restrict__ cb,
    const float* __restrict__ scales, const int* __restrict__ idx,
    const int* __restrict__ signs, float* __restrict__ out)
{
  __shared__ float Xs[32][33];
  __shared__ float Ws[32][33];
  const int t = threadIdx.x;
  const int tx = t & 31, ty = t >> 5;
  const int brow = blockIdx.y * 32, bcol = blockIdx.x * 32;
  float acc[4] = {0.f, 0.f, 0.f, 0.f};

  for (int k0 = 0; k0 < K_; k0 += 32) {
    for (int l = t; l < 1024; l += 256) {
      const int r = l >> 5, c = l & 31;
      Xs[r][c] = x[(size_t)(brow + r) * K_ + k0 + c];
      const int n = bcol + r;
      const size_t flat = (size_t)n * K_ + (k0 + c);
      const int g = (int)(flat >> 3), j = (int)(flat & 7);
      float wv = cb[idx[g] * 8 + j] * scales[n];
      if (!((signs[g] >> (7 - j)) & 1)) wv = -wv;
      Ws[r][c] = wv;
    }
    __syncthreads();
#pragma unroll
    for (int kk = 0; kk < 32; ++kk) {
      const float wv = Ws[tx][kk];
      acc[0] += Xs[ty][kk] * wv;
      acc[1] += Xs[ty + 8][kk] * wv;
      acc[2] += Xs[ty + 16][kk] * wv;
      acc[3] += Xs[ty + 24][kk] * wv;
    }
    __syncthreads();
  }
#pragma unroll
  for (int q = 0; q < 4; ++q)
    out[(size_t)(brow + ty + 8 * q) * N_ + bcol + tx] = acc[q];
}

// ---------------------------------------------------------------------------
extern "C" void kernel_launch(void* const* d_in, const int* in_sizes, int n_in,
                              void* d_out, int out_size, void* d_ws, size_t ws_size,
                              hipStream_t stream)
{
  const float* x      = (const float*)d_in[0];
  const float* cb     = (const float*)d_in[1];
  const float* scales = (const float*)d_in[2];
  const int*   idx    = (const int*)d_in[3];
  const int*   signs  = (const int*)d_in[4];
  float* out = (float*)d_out;

  const size_t wbytes = (size_t)N_ * K_ * 2;
  const size_t xbytes = (size_t)M_ * K_ * 2;

  if (ws_size >= wbytes + xbytes) {
    unsigned short* Wb = (unsigned short*)d_ws;
    unsigned short* Xb = (unsigned short*)((char*)d_ws + wbytes);
    dequant_w_kernel<<<(N_ * K_ / 8) / 256, 256, 0, stream>>>(cb, scales, idx, signs, Wb);
    cvt_x_kernel<<<(M_ * K_ / 8) / 256, 256, 0, stream>>>(x, Xb);
    gemm256_kernel<<<(M_ / BM) * (N_ / BN), 512, 0, stream>>>(Xb, Wb, out);
  } else {
    fallback_kernel<<<dim3(N_ / 32, M_ / 32), 256, 0, stream>>>(x, cb, scales, idx, signs, out);
  }
}